// Round 8
// baseline (294.261 us; speedup 1.0000x reference)
//
#include <hip/hip_runtime.h>
#include <stdint.h>

#define DM    1024
#define NH    16
#define HS    64
#define S_LEN 2048

typedef short bf16x8 __attribute__((ext_vector_type(8)));
typedef float f32x4  __attribute__((ext_vector_type(4)));
typedef unsigned short u16x4 __attribute__((ext_vector_type(4)));

__device__ __forceinline__ uint16_t f2b(float f) {
    union { float f; uint32_t i; } x; x.f = f;
    uint32_t r = x.i + 0x7fffu + ((x.i >> 16) & 1u);
    return (uint16_t)(r >> 16);
}
__device__ __forceinline__ uint32_t pack2(float a, float b) {
    return (uint32_t)f2b(a) | ((uint32_t)f2b(b) << 16);
}
__device__ __forceinline__ f32x4 mfma16(bf16x8 a, bf16x8 b, f32x4 c) {
    return __builtin_amdgcn_mfma_f32_16x16x32_bf16(a, b, c, 0, 0, 0);
}
// native 2^x (one v_exp_f32). NOTE: __exp2f does not exist in this toolchain.
__device__ __forceinline__ float fast_exp2(float x) {
    return __builtin_amdgcn_exp2f(x);
}
// 16-lane-row max reduce step via DPP (VALU pipe, no LDS). CTRL must be an ICE.
template<int CTRL>
__device__ __forceinline__ float dpp_max(float x) {
    union { float f; int i; } u; u.f = x;
    int y = __builtin_amdgcn_update_dpp(u.i, u.i, CTRL, 0xF, 0xF, true);
    union { int i; float f; } v; v.i = y;
    return fmaxf(x, v.f);
}

// ---- One-time x (fp32) -> bf16 convert: 8 elems/thread ----
__global__ __launch_bounds__(256) void convert_bf16(
    const float* __restrict__ in, uint16_t* __restrict__ out)
{
    const size_t i = (size_t)blockIdx.x * 256 + threadIdx.x;
    const float4* p = (const float4*)in + i * 2;
    float4 a = p[0], b = p[1];
    uint4 o;
    o.x = pack2(a.x, a.y); o.y = pack2(a.z, a.w);
    o.z = pack2(b.x, b.y); o.w = pack2(b.z, b.w);
    ((uint4*)out)[i] = o;
}

// ---- One-time W (K=1024 x N fp32) -> WT (N x 1024 bf16) transpose ----
__global__ __launch_bounds__(256) void transpose_w(
    const float* __restrict__ W, uint16_t* __restrict__ WT, int N)
{
    __shared__ float T[32][33];
    const int tx = threadIdx.x & 31, ty = threadIdx.x >> 5;
    const int n0 = blockIdx.x * 32, k0 = blockIdx.y * 32;
    #pragma unroll
    for (int i = 0; i < 4; ++i)
        T[ty + i * 8][tx] = W[(size_t)(k0 + ty + i * 8) * N + n0 + tx];
    __syncthreads();
    #pragma unroll
    for (int i = 0; i < 4; ++i)
        WT[(size_t)(n0 + ty + i * 8) * 1024 + k0 + tx] = f2b(T[tx][ty + i * 8]);
}

// ---- Reg-staging macros (fp32-A fallback path only) ----
#define LOADK(K0, A0_, A1_, B0_, B1_)                                                      \
    do {                                                                                   \
        if (ABF) {                                                                         \
            const uint16_t* ap_ = (const uint16_t*)Araw + (size_t)(m0 + sm) * 1024 + (K0) + skc; \
            A0_ = *(const uint4*)ap_;                                                      \
            A1_ = *(const uint4*)(ap_ + 8);                                                \
        } else {                                                                           \
            const float* ap_ = (const float*)Araw + (size_t)(m0 + sm) * 1024 + (K0) + skc; \
            float4 f0_ = *(const float4*)(ap_ + 0),  f1_ = *(const float4*)(ap_ + 4);      \
            float4 f2_ = *(const float4*)(ap_ + 8),  f3_ = *(const float4*)(ap_ + 12);     \
            A0_.x = pack2(f0_.x, f0_.y); A0_.y = pack2(f0_.z, f0_.w);                      \
            A0_.z = pack2(f1_.x, f1_.y); A0_.w = pack2(f1_.z, f1_.w);                      \
            A1_.x = pack2(f2_.x, f2_.y); A1_.y = pack2(f2_.z, f2_.w);                      \
            A1_.z = pack2(f3_.x, f3_.y); A1_.w = pack2(f3_.z, f3_.w);                      \
        }                                                                                  \
        const uint16_t* bp_ = BT + (size_t)(n0 + sm) * 1024 + (K0) + skc;                  \
        B0_ = *(const uint4*)bp_;                                                          \
        B1_ = *(const uint4*)(bp_ + 8);                                                    \
    } while (0)

#define STOREK(BUF, A0_, A1_, B0_, B1_)                                                    \
    do {                                                                                   \
        *(uint4*)&As[BUF][sm][skc]     = A0_;                                              \
        *(uint4*)&As[BUF][sm][skc + 8] = A1_;                                              \
        *(uint4*)&Bs[BUF][sm][skc]     = B0_;                                              \
        *(uint4*)&Bs[BUF][sm][skc + 8] = B1_;                                              \
    } while (0)

#define COMPUTEK(BUF)                                                                      \
    do {                                                                                   \
        bf16x8 af_[4], bf_[4];                                                             \
        _Pragma("unroll")                                                                  \
        for (int mi = 0; mi < 4; ++mi)                                                     \
            af_[mi] = *(const bf16x8*)&As[BUF][wm + mi * 16 + li][quad * 8];               \
        _Pragma("unroll")                                                                  \
        for (int ni = 0; ni < 4; ++ni)                                                     \
            bf_[ni] = *(const bf16x8*)&Bs[BUF][wn + ni * 16 + li][quad * 8];               \
        _Pragma("unroll")                                                                  \
        for (int mi = 0; mi < 4; ++mi)                                                     \
            _Pragma("unroll")                                                              \
            for (int ni = 0; ni < 4; ++ni)                                                 \
                acc[mi][ni] = mfma16(af_[mi], bf_[ni], acc[mi][ni]);                       \
    } while (0)

// Async global->LDS staging: per wave, 2x1KB per operand (16 rows x 64B each),
// wave-uniform LDS base + lane*16 (HW rule), per-lane global source address.
#define STAGE_GLL(BUF, K0)                                                                 \
    do {                                                                                   \
        const uint16_t* ga_ = (const uint16_t*)Araw +                                      \
            (size_t)(m0 + wave * 32 + (lane >> 2)) * 1024 + (K0) + (lane & 3) * 8;         \
        __builtin_amdgcn_global_load_lds(                                                  \
            (const __attribute__((address_space(1))) void*)ga_,                            \
            (__attribute__((address_space(3))) void*)&As[BUF][wave * 32][0], 16, 0, 0);    \
        __builtin_amdgcn_global_load_lds(                                                  \
            (const __attribute__((address_space(1))) void*)(ga_ + 16 * 1024),              \
            (__attribute__((address_space(3))) void*)&As[BUF][wave * 32 + 16][0], 16, 0, 0);\
        const uint16_t* gb_ = BT +                                                         \
            (size_t)(n0 + wave * 32 + (lane >> 2)) * 1024 + (K0) + (lane & 3) * 8;         \
        __builtin_amdgcn_global_load_lds(                                                  \
            (const __attribute__((address_space(1))) void*)gb_,                            \
            (__attribute__((address_space(3))) void*)&Bs[BUF][wave * 32][0], 16, 0, 0);    \
        __builtin_amdgcn_global_load_lds(                                                  \
            (const __attribute__((address_space(1))) void*)(gb_ + 16 * 1024),              \
            (__attribute__((address_space(3))) void*)&Bs[BUF][wave * 32 + 16][0], 16, 0, 0);\
    } while (0)

// ---- MFMA GEMM: C(M x N) = A(M x 1024) @ BT^T + bias ----
// ABF path: double-buffered global_load_lds staging (no VGPR round-trip),
// one barrier per k-tile; __syncthreads provides the vmcnt drain.
// MODE 0: N=3072 fused RoPE/split epilogue (WV: also emit V as bf16 [bh][hd][s]);
//         q pre-scaled by 0.125*log2(e) so attn uses native exp2. MODE 1: fp32 out.
template<int MODE, bool ABF, bool WV>
__global__ __launch_bounds__(256) void gemm_mfma(
    const void* __restrict__ Araw,
    const uint16_t* __restrict__ BT,
    const float* __restrict__ bias,
    int N,
    const float* __restrict__ cq, const float* __restrict__ sq,
    const float* __restrict__ ck, const float* __restrict__ sk,
    uint16_t* __restrict__ qbuf, uint16_t* __restrict__ kbuf,
    float* __restrict__ kout, float* __restrict__ vout,
    uint16_t* __restrict__ vtb,
    float* __restrict__ Cout)
{
    __shared__ uint16_t As[2][128][32];   // linear (GLL requires contiguous dest)
    __shared__ uint16_t Bs[2][128][32];

    const int tid  = threadIdx.x;
    const int wave = tid >> 6, lane = tid & 63;
    const int quad = lane >> 4, li = lane & 15;
    const int wm = (wave >> 1) * 64, wn = (wave & 1) * 64;
    const int m0 = blockIdx.y * 128, n0 = blockIdx.x * 128;

    f32x4 acc[4][4];
    #pragma unroll
    for (int a = 0; a < 4; ++a)
        #pragma unroll
        for (int c = 0; c < 4; ++c)
            acc[a][c] = (f32x4){0.f, 0.f, 0.f, 0.f};

    const int sm = tid >> 1, skc = (tid & 1) * 16;

    if constexpr (ABF) {
        STAGE_GLL(0, 0);
        __syncthreads();                        // vmcnt drained -> buf0 ready
        for (int t = 0; t < 32; t += 2) {
            if (t + 1 < 32) STAGE_GLL(1, (t + 1) * 32);   // async under compute
            COMPUTEK(0);
            __syncthreads();                    // buf1 ready; all done reading buf0
            if (t + 2 < 32) STAGE_GLL(0, (t + 2) * 32);
            COMPUTEK(1);
            __syncthreads();
        }
    } else {
        uint4 Aa0, Aa1, Ba0, Ba1;
        uint4 Ab0, Ab1, Bb0, Bb1;
        LOADK(0, Aa0, Aa1, Ba0, Ba1);
        STOREK(0, Aa0, Aa1, Ba0, Ba1);
        LOADK(32, Ab0, Ab1, Bb0, Bb1);
        __syncthreads();
        for (int t = 0; t < 16; ++t) {
            const int kb = t * 64;
            if (t < 15) LOADK(kb + 64, Aa0, Aa1, Ba0, Ba1);
            COMPUTEK(0);
            STOREK(1, Ab0, Ab1, Bb0, Bb1);
            __syncthreads();
            if (t < 15) LOADK(kb + 96, Ab0, Ab1, Bb0, Bb1);
            COMPUTEK(1);
            if (t < 15) {
                STOREK(0, Aa0, Aa1, Ba0, Ba1);
                __syncthreads();
            }
        }
    }

    if (MODE == 1) {
        #pragma unroll
        for (int ni = 0; ni < 4; ++ni) {
            const int n = n0 + wn + ni * 16 + li;
            const float bb = bias[n];
            #pragma unroll
            for (int mi = 0; mi < 4; ++mi)
                #pragma unroll
                for (int r = 0; r < 4; ++r) {
                    const int m = m0 + wm + mi * 16 + quad * 4 + r;
                    Cout[(size_t)m * N + n] = acc[mi][ni][r] + bb;
                }
        }
    } else {
        #pragma unroll
        for (int ni = 0; ni < 4; ++ni) {
            const int n   = n0 + wn + ni * 16 + li;
            const int sel = n >> 10;        // 0=q 1=k 2=v (wave-uniform per ni)
            const int d   = n & 1023;
            const int h   = d >> 6;
            const int hd  = d & 63;
            const int i0  = hd >> 1;
            const float bb = bias[n];
            #pragma unroll
            for (int mi = 0; mi < 4; ++mi) {
                const int mb = m0 + wm + mi * 16 + quad * 4;
                const int b  = mb >> 11;
                const int s0 = mb & 2047;
                float vv[4];
                #pragma unroll
                for (int r = 0; r < 4; ++r) {
                    const int s = s0 + r;
                    const float val  = acc[mi][ni][r] + bb;
                    const float part = __shfl_xor(val, 1);   // RoPE partner (n^1)
                    const size_t idx = ((size_t)(b * NH + h) * S_LEN + s) * HS + hd;
                    if (sel == 0) {
                        float c = cq[s * 32 + i0], sn = sq[s * 32 + i0];
                        float o = (hd & 1) ? (part * sn + val * c) : (val * c - part * sn);
                        qbuf[idx] = f2b(o * 0.18033688f);    // 1/sqrt(HS) * log2(e)
                    } else if (sel == 1) {
                        kout[idx] = val;                     // kv[0] = pre-rotary k
                        float c = ck[s * 32 + i0], sn = sk[s * 32 + i0];
                        float o = (hd & 1) ? (part * sn + val * c) : (val * c - part * sn);
                        kbuf[idx] = f2b(o);
                    } else {
                        vout[idx] = val;                     // kv[1] = v
                        vv[r] = val;
                    }
                }
                if (WV && sel == 2) {
                    u16x4 u;
                    u[0] = f2b(vv[0]); u[1] = f2b(vv[1]);
                    u[2] = f2b(vv[2]); u[3] = f2b(vv[3]);
                    *(u16x4*)&vtb[((size_t)(b * NH + h) * HS + hd) * S_LEN + s0] = u;
                }
            }
        }
    }
}

// ---- MFMA flash attention: block = (b,h) x 64-query tile, 4 waves x 16 rows ----
// V pre-transposed bf16 [bh][hd][s]. Q fragments loaded direct from global (no Qs LDS).
// Softmax in log2 domain (q pre-scaled by log2e): native v_exp_f32.
// Row-max via DPP; row-sum via MFMA with ones-B (C-layout match).
__global__ __launch_bounds__(256) void attn_mfma(
    const uint16_t* __restrict__ qbuf,
    const uint16_t* __restrict__ kbuf,
    const uint16_t* __restrict__ vtb,
    uint16_t* __restrict__ obuf)
{
    __shared__ uint16_t Ks[64][72];
    __shared__ uint16_t Vt[64][72];   // [hs][key]
    __shared__ uint16_t Ps[64][68];   // stride 68 (34 dw): conflict-free writes+reads

    const int i  = blockIdx.x;
    const int bh = i >> 5;
    const int jj = i & 31;
    const int g  = jj >> 3, cc = jj & 7;
    const int qt = (g == 0) ? (31 - cc) : (g == 1) ? cc : (g == 2) ? (23 - cc) : (8 + cc);
    const int h = bh & 15, b = bh >> 4;
    const int tid = threadIdx.x;
    const int wave = tid >> 6, lane = tid & 63;
    const int quad = lane >> 4, li = lane & 15;
    const int wrow0 = wave * 16;

    const short onebf = (short)0x3F80;   // bf16 1.0
    const bf16x8 kOnes = {onebf, onebf, onebf, onebf, onebf, onebf, onebf, onebf};

    // Q fragments direct from global: lane reads rows wrow0+li, cols quad*8(+32)
    const uint16_t* qp = qbuf + ((size_t)bh * S_LEN + qt * 64 + wrow0 + li) * HS + quad * 8;
    const bf16x8 aq0 = *(const bf16x8*)qp;
    const bf16x8 aq1 = *(const bf16x8*)(qp + 32);

    f32x4 oacc[4];
    float m_i[4], l_i[4];
    #pragma unroll
    for (int r = 0; r < 4; ++r) {
        m_i[r] = -1e30f; l_i[r] = 0.f;
        oacc[r] = (f32x4){0.f, 0.f, 0.f, 0.f};
    }

    const int row = tid >> 2, c = (tid & 3) * 16;         // shared staging coords
    uint4 kr0, kr1, vr0, vr1;

    auto load_kv = [&](int kt) {
        const uint16_t* kp = kbuf + ((size_t)bh * S_LEN + kt * 64 + row) * HS + c;
        kr0 = *(const uint4*)kp;
        kr1 = *(const uint4*)(kp + 8);
        const uint16_t* vp = vtb + ((size_t)bh * HS + row) * S_LEN + kt * 64 + c;
        vr0 = *(const uint4*)vp;
        vr1 = *(const uint4*)(vp + 8);
    };
    load_kv(0);

    for (int kt = 0; kt <= qt; ++kt) {
        __syncthreads();   // previous tile's LDS consumers done
        *(uint4*)&Ks[row][c]     = kr0;
        *(uint4*)&Ks[row][c + 8] = kr1;
        *(uint4*)&Vt[row][c]     = vr0;
        *(uint4*)&Vt[row][c + 8] = vr1;
        __syncthreads();
        if (kt < qt) load_kv(kt + 1);   // prefetch next tile under compute

        // S' = Q' K^T in log2 domain (q pre-scaled by 0.125*log2e)
        f32x4 sacc[4];
        __builtin_amdgcn_s_setprio(1);
        #pragma unroll
        for (int ni = 0; ni < 4; ++ni) {
            bf16x8 b0 = *(const bf16x8*)&Ks[ni * 16 + li][quad * 8];
            bf16x8 b1 = *(const bf16x8*)&Ks[ni * 16 + li][32 + quad * 8];
            f32x4 z = (f32x4){0.f, 0.f, 0.f, 0.f};
            z = mfma16(aq0, b0, z);
            sacc[ni] = mfma16(aq1, b1, z);
        }
        __builtin_amdgcn_s_setprio(0);

        // online softmax (C-layout: row = quad*4+r, col = ni*16+li)
        const bool diag = (kt == qt);
        float p[4][4];
        #pragma unroll
        for (int ni = 0; ni < 4; ++ni)
            #pragma unroll
            for (int r = 0; r < 4; ++r) {
                float v = sacc[ni][r];
                if (diag && (ni * 16 + li > wrow0 + quad * 4 + r)) v = -65504.f;
                p[ni][r] = v;
            }
        float alp[4];
        #pragma unroll
        for (int r = 0; r < 4; ++r) {
            float mx = fmaxf(fmaxf(p[0][r], p[1][r]), fmaxf(p[2][r], p[3][r]));
            mx = dpp_max<0xB1>(mx);    // quad_perm [1,0,3,2]  (xor 1)
            mx = dpp_max<0x4E>(mx);    // quad_perm [2,3,0,1]  (xor 2)
            mx = dpp_max<0x124>(mx);   // row_ror:4
            mx = dpp_max<0x128>(mx);   // row_ror:8  -> all-16-lane max
            float mnew  = fmaxf(m_i[r], mx);
            alp[r] = fast_exp2(m_i[r] - mnew);
            m_i[r] = mnew;
            #pragma unroll
            for (int ni = 0; ni < 4; ++ni)
                p[ni][r] = fast_exp2(p[ni][r] - mnew);
            #pragma unroll
            for (int ni = 0; ni < 4; ++ni) oacc[ni][r] *= alp[r];
        }

        // P: C-layout -> A-layout via wave-private LDS slab
        #pragma unroll
        for (int ni = 0; ni < 4; ++ni)
            #pragma unroll
            for (int r = 0; r < 4; ++r)
                Ps[wrow0 + quad * 4 + r][ni * 16 + li] = f2b(p[ni][r]);

        bf16x8 pa0 = *(const bf16x8*)&Ps[wrow0 + li][quad * 8];
        bf16x8 pa1 = *(const bf16x8*)&Ps[wrow0 + li][32 + quad * 8];

        // row-sum via MFMA with B=ones: ls[r] lands in same per-lane slot as sacc
        __builtin_amdgcn_s_setprio(1);
        f32x4 ls = (f32x4){0.f, 0.f, 0.f, 0.f};
        ls = mfma16(pa0, kOnes, ls);
        ls = mfma16(pa1, kOnes, ls);

        // O += P @ V
        #pragma unroll
        for (int ni = 0; ni < 4; ++ni) {
            bf16x8 v0 = *(const bf16x8*)&Vt[ni * 16 + li][quad * 8];
            bf16x8 v1 = *(const bf16x8*)&Vt[ni * 16 + li][32 + quad * 8];
            oacc[ni] = mfma16(pa0, v0, oacc[ni]);
            oacc[ni] = mfma16(pa1, v1, oacc[ni]);
        }
        __builtin_amdgcn_s_setprio(0);

        #pragma unroll
        for (int r = 0; r < 4; ++r)
            l_i[r] = l_i[r] * alp[r] + ls[r];
    }

    #pragma unroll
    for (int ni = 0; ni < 4; ++ni)
        #pragma unroll
        for (int r = 0; r < 4; ++r) {
            const int qg = qt * 64 + wrow0 + quad * 4 + r;
            obuf[((size_t)b * S_LEN + qg) * DM + h * HS + ni * 16 + li] =
                f2b(oacc[ni][r] / l_i[r]);
        }
}

extern "C" void kernel_launch(void* const* d_in, const int* in_sizes, int n_in,
                              void* d_out, int out_size, void* d_ws, size_t ws_size,
                              hipStream_t stream) {
    const float* x  = (const float*)d_in[0];
    const float* cq = (const float*)d_in[1];
    const float* sq = (const float*)d_in[2];
    const float* ck = (const float*)d_in[3];
    const float* sk = (const float*)d_in[4];
    // d_in[5]: causal tril mask (int32) — structure known, not re-read
    const float* Wp = (const float*)d_in[6];
    const float* bp = (const float*)d_in[7];
    const float* Wf = (const float*)d_in[8];
    const float* bf = (const float*)d_in[9];

    float* out  = (float*)d_out;
    float* ffo  = out;                 // (B,S,DM) fp32
    float* kout = out + 4194304;       // kv[0] = pre-rotary k (B,NH,S,HS) fp32
    float* vout = out + 8388608;       // kv[1] = v fp32

    uint16_t* qbuf = (uint16_t*)d_ws;  // RoPE'd q bf16 (pre-scaled)    [0,8M)
    uint16_t* kbuf = qbuf + 4194304;   // RoPE'd k bf16                 [8M,16M)
    uint16_t* abuf = kbuf + 4194304;   // attn_o bf16                   [16M,24M)
    uint16_t* vtb  = abuf + 4194304;   // V bf16 [bh][hd][s]            [24M,32M)
    uint16_t* xbf  = vtb  + 4194304;   // x bf16                        [32M,40M)
    uint16_t* WpT  = abuf;             // alias: dead before attn writes abuf
    uint16_t* WfT  = qbuf;             // alias: qbuf dead after attn

    const bool has_xbf = ws_size >= (size_t)40 * 1024 * 1024;

    dim3 blk(256);
    transpose_w<<<dim3(96, 32), blk, 0, stream>>>(Wp, WpT, 3072);
    if (has_xbf) {
        convert_bf16<<<dim3(2048), blk, 0, stream>>>(x, xbf);
        gemm_mfma<0, true, true><<<dim3(24, 32), blk, 0, stream>>>(
            xbf, WpT, bp, 3072, cq, sq, ck, sk,
            qbuf, kbuf, kout, vout, vtb, nullptr);
    } else {
        gemm_mfma<0, false, true><<<dim3(24, 32), blk, 0, stream>>>(
            x, WpT, bp, 3072, cq, sq, ck, sk,
            qbuf, kbuf, kout, vout, vtb, nullptr);
    }
    attn_mfma<<<dim3(1024), blk, 0, stream>>>(qbuf, kbuf, vtb, abuf);
    transpose_w<<<dim3(32, 32), blk, 0, stream>>>(Wf, WfT, 1024);
    gemm_mfma<1, true, false><<<dim3(8, 32), blk, 0, stream>>>(
        abuf, WfT, bf, 1024, nullptr, nullptr, nullptr, nullptr,
        nullptr, nullptr, nullptr, nullptr, nullptr, ffo);
}

// Round 9
// 275.947 us; speedup vs baseline: 1.0664x; 1.0664x over previous
//
#include <hip/hip_runtime.h>
#include <stdint.h>

#define DM    1024
#define NH    16
#define HS    64
#define S_LEN 2048

typedef short bf16x8 __attribute__((ext_vector_type(8)));
typedef float f32x4  __attribute__((ext_vector_type(4)));
typedef unsigned short u16x4 __attribute__((ext_vector_type(4)));

__device__ __forceinline__ uint16_t f2b(float f) {
    union { float f; uint32_t i; } x; x.f = f;
    uint32_t r = x.i + 0x7fffu + ((x.i >> 16) & 1u);
    return (uint16_t)(r >> 16);
}
__device__ __forceinline__ uint32_t pack2(float a, float b) {
    return (uint32_t)f2b(a) | ((uint32_t)f2b(b) << 16);
}
__device__ __forceinline__ f32x4 mfma16(bf16x8 a, bf16x8 b, f32x4 c) {
    return __builtin_amdgcn_mfma_f32_16x16x32_bf16(a, b, c, 0, 0, 0);
}
// native 2^x (one v_exp_f32). NOTE: __exp2f does not exist in this toolchain.
__device__ __forceinline__ float fast_exp2(float x) {
    return __builtin_amdgcn_exp2f(x);
}
// 16-lane-row max reduce step via DPP (VALU pipe, no LDS). CTRL must be an ICE.
template<int CTRL>
__device__ __forceinline__ float dpp_max(float x) {
    union { float f; int i; } u; u.f = x;
    int y = __builtin_amdgcn_update_dpp(u.i, u.i, CTRL, 0xF, 0xF, true);
    union { int i; float f; } v; v.i = y;
    return fmaxf(x, v.f);
}

// ---- One-time x (fp32) -> bf16 convert: 8 elems/thread ----
__global__ __launch_bounds__(256) void convert_bf16(
    const float* __restrict__ in, uint16_t* __restrict__ out)
{
    const size_t i = (size_t)blockIdx.x * 256 + threadIdx.x;
    const float4* p = (const float4*)in + i * 2;
    float4 a = p[0], b = p[1];
    uint4 o;
    o.x = pack2(a.x, a.y); o.y = pack2(a.z, a.w);
    o.z = pack2(b.x, b.y); o.w = pack2(b.z, b.w);
    ((uint4*)out)[i] = o;
}

// ---- One-time W (K=1024 x N fp32) -> WT (N x 1024 bf16) transpose ----
__global__ __launch_bounds__(256) void transpose_w(
    const float* __restrict__ W, uint16_t* __restrict__ WT, int N)
{
    __shared__ float T[32][33];
    const int tx = threadIdx.x & 31, ty = threadIdx.x >> 5;
    const int n0 = blockIdx.x * 32, k0 = blockIdx.y * 32;
    #pragma unroll
    for (int i = 0; i < 4; ++i)
        T[ty + i * 8][tx] = W[(size_t)(k0 + ty + i * 8) * N + n0 + tx];
    __syncthreads();
    #pragma unroll
    for (int i = 0; i < 4; ++i)
        WT[(size_t)(n0 + ty + i * 8) * 1024 + k0 + tx] = f2b(T[tx][ty + i * 8]);
}

// ---- Reg-staging macros (fp32-A fallback path; 512 threads, 8 elems/thread) ----
#define LOADK(K0, A_, B_)                                                                  \
    do {                                                                                   \
        if (ABF) {                                                                         \
            const uint16_t* ap_ = (const uint16_t*)Araw + (size_t)(m0 + sm) * 1024 + (K0) + skc; \
            A_ = *(const uint4*)ap_;                                                       \
        } else {                                                                           \
            const float* ap_ = (const float*)Araw + (size_t)(m0 + sm) * 1024 + (K0) + skc; \
            float4 f0_ = *(const float4*)(ap_ + 0),  f1_ = *(const float4*)(ap_ + 4);      \
            A_.x = pack2(f0_.x, f0_.y); A_.y = pack2(f0_.z, f0_.w);                        \
            A_.z = pack2(f1_.x, f1_.y); A_.w = pack2(f1_.z, f1_.w);                        \
        }                                                                                  \
        const uint16_t* bp_ = BT + (size_t)(n0 + sm) * 1024 + (K0) + skc;                  \
        B_ = *(const uint4*)bp_;                                                           \
    } while (0)

#define STOREK(BUF, A_, B_)                                                                \
    do {                                                                                   \
        *(uint4*)&As[BUF][sm][skc] = A_;                                                   \
        *(uint4*)&Bs[BUF][sm][skc] = B_;                                                   \
    } while (0)

// 8-wave compute: per-wave 32x64 output -> acc[2][4], 8 MFMA per k-step.
#define COMPUTEK(BUF)                                                                      \
    do {                                                                                   \
        bf16x8 af_[2], bf_[4];                                                             \
        _Pragma("unroll")                                                                  \
        for (int mi = 0; mi < 2; ++mi)                                                     \
            af_[mi] = *(const bf16x8*)&As[BUF][wm + mi * 16 + li][quad * 8];               \
        _Pragma("unroll")                                                                  \
        for (int ni = 0; ni < 4; ++ni)                                                     \
            bf_[ni] = *(const bf16x8*)&Bs[BUF][wn + ni * 16 + li][quad * 8];               \
        _Pragma("unroll")                                                                  \
        for (int mi = 0; mi < 2; ++mi)                                                     \
            _Pragma("unroll")                                                              \
            for (int ni = 0; ni < 4; ++ni)                                                 \
                acc[mi][ni] = mfma16(af_[mi], bf_[ni], acc[mi][ni]);                       \
    } while (0)

// Async global->LDS staging, 512 threads: ONE global_load_lds per operand covers
// the full 128x32 tile (512 lanes x 16B). Wave w's lanes fill rows [w*16,w*16+16).
#define STAGE_GLL(BUF, K0)                                                                 \
    do {                                                                                   \
        const uint16_t* ga_ = (const uint16_t*)Araw +                                      \
            (size_t)(m0 + wave * 16 + (lane >> 2)) * 1024 + (K0) + (lane & 3) * 8;         \
        __builtin_amdgcn_global_load_lds(                                                  \
            (const __attribute__((address_space(1))) void*)ga_,                            \
            (__attribute__((address_space(3))) void*)&As[BUF][wave * 16][0], 16, 0, 0);    \
        const uint16_t* gb_ = BT +                                                         \
            (size_t)(n0 + wave * 16 + (lane >> 2)) * 1024 + (K0) + (lane & 3) * 8;         \
        __builtin_amdgcn_global_load_lds(                                                  \
            (const __attribute__((address_space(1))) void*)gb_,                            \
            (__attribute__((address_space(3))) void*)&Bs[BUF][wave * 16][0], 16, 0, 0);    \
    } while (0)

// ---- MFMA GEMM: C(M x N) = A(M x 1024) @ BT^T + bias ----
// 512 threads / 8 waves (4m x 2n), 128x128 tile: 6 waves/SIMD at 3 blocks/CU for
// TLP latency hiding (R8 diagnosis: 2-phase barrier drain is latency-bound).
// MODE 0: N=3072 fused RoPE/split epilogue (WV: also emit V as bf16 [bh][hd][s]);
//         q pre-scaled by 0.125*log2(e) so attn uses native exp2. MODE 1: fp32 out.
template<int MODE, bool ABF, bool WV>
__global__ __launch_bounds__(512) void gemm_mfma(
    const void* __restrict__ Araw,
    const uint16_t* __restrict__ BT,
    const float* __restrict__ bias,
    int N,
    const float* __restrict__ cq, const float* __restrict__ sq,
    const float* __restrict__ ck, const float* __restrict__ sk,
    uint16_t* __restrict__ qbuf, uint16_t* __restrict__ kbuf,
    float* __restrict__ kout, float* __restrict__ vout,
    uint16_t* __restrict__ vtb,
    float* __restrict__ Cout)
{
    __shared__ uint16_t As[2][128][32];   // linear (GLL requires contiguous dest)
    __shared__ uint16_t Bs[2][128][32];

    const int tid  = threadIdx.x;
    const int wave = tid >> 6, lane = tid & 63;
    const int quad = lane >> 4, li = lane & 15;
    const int wm = (wave >> 1) * 32, wn = (wave & 1) * 64;
    const int m0 = blockIdx.y * 128, n0 = blockIdx.x * 128;

    f32x4 acc[2][4];
    #pragma unroll
    for (int a = 0; a < 2; ++a)
        #pragma unroll
        for (int c = 0; c < 4; ++c)
            acc[a][c] = (f32x4){0.f, 0.f, 0.f, 0.f};

    const int sm = tid >> 2, skc = (tid & 3) * 8;

    if constexpr (ABF) {
        STAGE_GLL(0, 0);
        __syncthreads();                        // vmcnt drained -> buf0 ready
        for (int t = 0; t < 32; t += 2) {
            if (t + 1 < 32) STAGE_GLL(1, (t + 1) * 32);   // async under compute
            COMPUTEK(0);
            __syncthreads();                    // buf1 ready; all done reading buf0
            if (t + 2 < 32) STAGE_GLL(0, (t + 2) * 32);
            COMPUTEK(1);
            __syncthreads();
        }
    } else {
        uint4 Aa, Ba, Ab, Bb;
        LOADK(0, Aa, Ba);
        STOREK(0, Aa, Ba);
        LOADK(32, Ab, Bb);
        __syncthreads();
        for (int t = 0; t < 16; ++t) {
            const int kb = t * 64;
            if (t < 15) LOADK(kb + 64, Aa, Ba);
            COMPUTEK(0);
            STOREK(1, Ab, Bb);
            __syncthreads();
            if (t < 15) LOADK(kb + 96, Ab, Bb);
            COMPUTEK(1);
            if (t < 15) {
                STOREK(0, Aa, Ba);
                __syncthreads();
            }
        }
    }

    if (MODE == 1) {
        #pragma unroll
        for (int ni = 0; ni < 4; ++ni) {
            const int n = n0 + wn + ni * 16 + li;
            const float bb = bias[n];
            #pragma unroll
            for (int mi = 0; mi < 2; ++mi)
                #pragma unroll
                for (int r = 0; r < 4; ++r) {
                    const int m = m0 + wm + mi * 16 + quad * 4 + r;
                    Cout[(size_t)m * N + n] = acc[mi][ni][r] + bb;
                }
        }
    } else {
        #pragma unroll
        for (int ni = 0; ni < 4; ++ni) {
            const int n   = n0 + wn + ni * 16 + li;
            const int sel = n >> 10;        // 0=q 1=k 2=v (wave-uniform per ni)
            const int d   = n & 1023;
            const int h   = d >> 6;
            const int hd  = d & 63;
            const int i0  = hd >> 1;
            const float bb = bias[n];
            #pragma unroll
            for (int mi = 0; mi < 2; ++mi) {
                const int mb = m0 + wm + mi * 16 + quad * 4;
                const int b  = mb >> 11;
                const int s0 = mb & 2047;
                float vv[4];
                #pragma unroll
                for (int r = 0; r < 4; ++r) {
                    const int s = s0 + r;
                    const float val  = acc[mi][ni][r] + bb;
                    const float part = __shfl_xor(val, 1);   // RoPE partner (n^1)
                    const size_t idx = ((size_t)(b * NH + h) * S_LEN + s) * HS + hd;
                    if (sel == 0) {
                        float c = cq[s * 32 + i0], sn = sq[s * 32 + i0];
                        float o = (hd & 1) ? (part * sn + val * c) : (val * c - part * sn);
                        qbuf[idx] = f2b(o * 0.18033688f);    // 1/sqrt(HS) * log2(e)
                    } else if (sel == 1) {
                        kout[idx] = val;                     // kv[0] = pre-rotary k
                        float c = ck[s * 32 + i0], sn = sk[s * 32 + i0];
                        float o = (hd & 1) ? (part * sn + val * c) : (val * c - part * sn);
                        kbuf[idx] = f2b(o);
                    } else {
                        vout[idx] = val;                     // kv[1] = v
                        vv[r] = val;
                    }
                }
                if (WV && sel == 2) {
                    u16x4 u;
                    u[0] = f2b(vv[0]); u[1] = f2b(vv[1]);
                    u[2] = f2b(vv[2]); u[3] = f2b(vv[3]);
                    *(u16x4*)&vtb[((size_t)(b * NH + h) * HS + hd) * S_LEN + s0] = u;
                }
            }
        }
    }
}

// ---- MFMA flash attention: block = (b,h) x 64-query tile, 4 waves x 16 rows ----
// V pre-transposed bf16 [bh][hd][s]. Q fragments loaded direct from global (no Qs LDS).
// Softmax in log2 domain (q pre-scaled by log2e): native v_exp_f32.
// Row-max via DPP; row-sum via MFMA with ones-B (C-layout match).
__global__ __launch_bounds__(256) void attn_mfma(
    const uint16_t* __restrict__ qbuf,
    const uint16_t* __restrict__ kbuf,
    const uint16_t* __restrict__ vtb,
    uint16_t* __restrict__ obuf)
{
    __shared__ uint16_t Ks[64][72];
    __shared__ uint16_t Vt[64][72];   // [hs][key]
    __shared__ uint16_t Ps[64][68];   // stride 68 (34 dw): conflict-free writes+reads

    const int i  = blockIdx.x;
    const int bh = i >> 5;
    const int jj = i & 31;
    const int g  = jj >> 3, cc = jj & 7;
    const int qt = (g == 0) ? (31 - cc) : (g == 1) ? cc : (g == 2) ? (23 - cc) : (8 + cc);
    const int h = bh & 15, b = bh >> 4;
    const int tid = threadIdx.x;
    const int wave = tid >> 6, lane = tid & 63;
    const int quad = lane >> 4, li = lane & 15;
    const int wrow0 = wave * 16;

    const short onebf = (short)0x3F80;   // bf16 1.0
    const bf16x8 kOnes = {onebf, onebf, onebf, onebf, onebf, onebf, onebf, onebf};

    // Q fragments direct from global: lane reads rows wrow0+li, cols quad*8(+32)
    const uint16_t* qp = qbuf + ((size_t)bh * S_LEN + qt * 64 + wrow0 + li) * HS + quad * 8;
    const bf16x8 aq0 = *(const bf16x8*)qp;
    const bf16x8 aq1 = *(const bf16x8*)(qp + 32);

    f32x4 oacc[4];
    float m_i[4], l_i[4];
    #pragma unroll
    for (int r = 0; r < 4; ++r) {
        m_i[r] = -1e30f; l_i[r] = 0.f;
        oacc[r] = (f32x4){0.f, 0.f, 0.f, 0.f};
    }

    const int row = tid >> 2, c = (tid & 3) * 16;         // shared staging coords
    uint4 kr0, kr1, vr0, vr1;

    auto load_kv = [&](int kt) {
        const uint16_t* kp = kbuf + ((size_t)bh * S_LEN + kt * 64 + row) * HS + c;
        kr0 = *(const uint4*)kp;
        kr1 = *(const uint4*)(kp + 8);
        const uint16_t* vp = vtb + ((size_t)bh * HS + row) * S_LEN + kt * 64 + c;
        vr0 = *(const uint4*)vp;
        vr1 = *(const uint4*)(vp + 8);
    };
    load_kv(0);

    for (int kt = 0; kt <= qt; ++kt) {
        __syncthreads();   // previous tile's LDS consumers done
        *(uint4*)&Ks[row][c]     = kr0;
        *(uint4*)&Ks[row][c + 8] = kr1;
        *(uint4*)&Vt[row][c]     = vr0;
        *(uint4*)&Vt[row][c + 8] = vr1;
        __syncthreads();
        if (kt < qt) load_kv(kt + 1);   // prefetch next tile under compute

        // S' = Q' K^T in log2 domain (q pre-scaled by 0.125*log2e)
        f32x4 sacc[4];
        __builtin_amdgcn_s_setprio(1);
        #pragma unroll
        for (int ni = 0; ni < 4; ++ni) {
            bf16x8 b0 = *(const bf16x8*)&Ks[ni * 16 + li][quad * 8];
            bf16x8 b1 = *(const bf16x8*)&Ks[ni * 16 + li][32 + quad * 8];
            f32x4 z = (f32x4){0.f, 0.f, 0.f, 0.f};
            z = mfma16(aq0, b0, z);
            sacc[ni] = mfma16(aq1, b1, z);
        }
        __builtin_amdgcn_s_setprio(0);

        // online softmax (C-layout: row = quad*4+r, col = ni*16+li)
        const bool diag = (kt == qt);
        float p[4][4];
        #pragma unroll
        for (int ni = 0; ni < 4; ++ni)
            #pragma unroll
            for (int r = 0; r < 4; ++r) {
                float v = sacc[ni][r];
                if (diag && (ni * 16 + li > wrow0 + quad * 4 + r)) v = -65504.f;
                p[ni][r] = v;
            }
        float alp[4];
        #pragma unroll
        for (int r = 0; r < 4; ++r) {
            float mx = fmaxf(fmaxf(p[0][r], p[1][r]), fmaxf(p[2][r], p[3][r]));
            mx = dpp_max<0xB1>(mx);    // quad_perm [1,0,3,2]  (xor 1)
            mx = dpp_max<0x4E>(mx);    // quad_perm [2,3,0,1]  (xor 2)
            mx = dpp_max<0x124>(mx);   // row_ror:4
            mx = dpp_max<0x128>(mx);   // row_ror:8  -> all-16-lane max
            float mnew  = fmaxf(m_i[r], mx);
            alp[r] = fast_exp2(m_i[r] - mnew);
            m_i[r] = mnew;
            #pragma unroll
            for (int ni = 0; ni < 4; ++ni)
                p[ni][r] = fast_exp2(p[ni][r] - mnew);
            #pragma unroll
            for (int ni = 0; ni < 4; ++ni) oacc[ni][r] *= alp[r];
        }

        // P: C-layout -> A-layout via wave-private LDS slab
        #pragma unroll
        for (int ni = 0; ni < 4; ++ni)
            #pragma unroll
            for (int r = 0; r < 4; ++r)
                Ps[wrow0 + quad * 4 + r][ni * 16 + li] = f2b(p[ni][r]);

        bf16x8 pa0 = *(const bf16x8*)&Ps[wrow0 + li][quad * 8];
        bf16x8 pa1 = *(const bf16x8*)&Ps[wrow0 + li][32 + quad * 8];

        // row-sum via MFMA with B=ones: ls[r] lands in same per-lane slot as sacc
        __builtin_amdgcn_s_setprio(1);
        f32x4 ls = (f32x4){0.f, 0.f, 0.f, 0.f};
        ls = mfma16(pa0, kOnes, ls);
        ls = mfma16(pa1, kOnes, ls);

        // O += P @ V
        #pragma unroll
        for (int ni = 0; ni < 4; ++ni) {
            bf16x8 v0 = *(const bf16x8*)&Vt[ni * 16 + li][quad * 8];
            bf16x8 v1 = *(const bf16x8*)&Vt[ni * 16 + li][32 + quad * 8];
            oacc[ni] = mfma16(pa0, v0, oacc[ni]);
            oacc[ni] = mfma16(pa1, v1, oacc[ni]);
        }
        __builtin_amdgcn_s_setprio(0);

        #pragma unroll
        for (int r = 0; r < 4; ++r)
            l_i[r] = l_i[r] * alp[r] + ls[r];
    }

    #pragma unroll
    for (int ni = 0; ni < 4; ++ni)
        #pragma unroll
        for (int r = 0; r < 4; ++r) {
            const int qg = qt * 64 + wrow0 + quad * 4 + r;
            obuf[((size_t)b * S_LEN + qg) * DM + h * HS + ni * 16 + li] =
                f2b(oacc[ni][r] / l_i[r]);
        }
}

extern "C" void kernel_launch(void* const* d_in, const int* in_sizes, int n_in,
                              void* d_out, int out_size, void* d_ws, size_t ws_size,
                              hipStream_t stream) {
    const float* x  = (const float*)d_in[0];
    const float* cq = (const float*)d_in[1];
    const float* sq = (const float*)d_in[2];
    const float* ck = (const float*)d_in[3];
    const float* sk = (const float*)d_in[4];
    // d_in[5]: causal tril mask (int32) — structure known, not re-read
    const float* Wp = (const float*)d_in[6];
    const float* bp = (const float*)d_in[7];
    const float* Wf = (const float*)d_in[8];
    const float* bf = (const float*)d_in[9];

    float* out  = (float*)d_out;
    float* ffo  = out;                 // (B,S,DM) fp32
    float* kout = out + 4194304;       // kv[0] = pre-rotary k (B,NH,S,HS) fp32
    float* vout = out + 8388608;       // kv[1] = v fp32

    uint16_t* qbuf = (uint16_t*)d_ws;  // RoPE'd q bf16 (pre-scaled)    [0,8M)
    uint16_t* kbuf = qbuf + 4194304;   // RoPE'd k bf16                 [8M,16M)
    uint16_t* abuf = kbuf + 4194304;   // attn_o bf16                   [16M,24M)
    uint16_t* vtb  = abuf + 4194304;   // V bf16 [bh][hd][s]            [24M,32M)
    uint16_t* xbf  = vtb  + 4194304;   // x bf16                        [32M,40M)
    uint16_t* WpT  = abuf;             // alias: dead before attn writes abuf
    uint16_t* WfT  = qbuf;             // alias: qbuf dead after attn

    const bool has_xbf = ws_size >= (size_t)40 * 1024 * 1024;

    dim3 blk(256), blkg(512);
    transpose_w<<<dim3(96, 32), blk, 0, stream>>>(Wp, WpT, 3072);
    if (has_xbf) {
        convert_bf16<<<dim3(2048), blk, 0, stream>>>(x, xbf);
        gemm_mfma<0, true, true><<<dim3(24, 32), blkg, 0, stream>>>(
            xbf, WpT, bp, 3072, cq, sq, ck, sk,
            qbuf, kbuf, kout, vout, vtb, nullptr);
    } else {
        gemm_mfma<0, false, true><<<dim3(24, 32), blkg, 0, stream>>>(
            x, WpT, bp, 3072, cq, sq, ck, sk,
            qbuf, kbuf, kout, vout, vtb, nullptr);
    }
    attn_mfma<<<dim3(1024), blk, 0, stream>>>(qbuf, kbuf, vtb, abuf);
    transpose_w<<<dim3(32, 32), blk, 0, stream>>>(Wf, WfT, 1024);
    gemm_mfma<1, true, false><<<dim3(8, 32), blkg, 0, stream>>>(
        abuf, WfT, bf, 1024, nullptr, nullptr, nullptr, nullptr,
        nullptr, nullptr, nullptr, nullptr, nullptr, ffo);
}

// Round 10
// 251.128 us; speedup vs baseline: 1.1718x; 1.0988x over previous
//
#include <hip/hip_runtime.h>
#include <stdint.h>

#define DM    1024
#define NH    16
#define HS    64
#define S_LEN 2048

typedef short bf16x8 __attribute__((ext_vector_type(8)));
typedef float f32x4  __attribute__((ext_vector_type(4)));
typedef unsigned short u16x4 __attribute__((ext_vector_type(4)));

__device__ __forceinline__ uint16_t f2b(float f) {
    union { float f; uint32_t i; } x; x.f = f;
    uint32_t r = x.i + 0x7fffu + ((x.i >> 16) & 1u);
    return (uint16_t)(r >> 16);
}
__device__ __forceinline__ uint32_t pack2(float a, float b) {
    return (uint32_t)f2b(a) | ((uint32_t)f2b(b) << 16);
}
__device__ __forceinline__ f32x4 mfma16(bf16x8 a, bf16x8 b, f32x4 c) {
    return __builtin_amdgcn_mfma_f32_16x16x32_bf16(a, b, c, 0, 0, 0);
}
// native 2^x (one v_exp_f32). NOTE: __exp2f does not exist in this toolchain.
__device__ __forceinline__ float fast_exp2(float x) {
    return __builtin_amdgcn_exp2f(x);
}
// 16-lane-row max reduce step via DPP (VALU pipe, no LDS). CTRL must be an ICE.
template<int CTRL>
__device__ __forceinline__ float dpp_max(float x) {
    union { float f; int i; } u; u.f = x;
    int y = __builtin_amdgcn_update_dpp(u.i, u.i, CTRL, 0xF, 0xF, true);
    union { int i; float f; } v; v.i = y;
    return fmaxf(x, v.f);
}

// ---- 32x32 fp32 -> bf16 transposed tile (shared by prep / transpose_w) ----
__device__ __forceinline__ void transpose_tile(
    const float* __restrict__ W, uint16_t* __restrict__ WT, int N,
    int n0, int k0, float (*T)[33])
{
    const int tx = threadIdx.x & 31, ty = threadIdx.x >> 5;
    #pragma unroll
    for (int i = 0; i < 4; ++i)
        T[ty + i * 8][tx] = W[(size_t)(k0 + ty + i * 8) * N + n0 + tx];
    __syncthreads();
    #pragma unroll
    for (int i = 0; i < 4; ++i)
        WT[(size_t)(n0 + ty + i * 8) * 1024 + k0 + tx] = f2b(T[tx][ty + i * 8]);
}

// ---- Fused prep: blocks [0,3072) transpose Wp; [3072,5120) convert x -> bf16 ----
__global__ __launch_bounds__(256) void prep(
    const float* __restrict__ x, uint16_t* __restrict__ xbf,
    const float* __restrict__ Wp, uint16_t* __restrict__ WpT)
{
    __shared__ float T[32][33];
    const int blk = blockIdx.x;
    if (blk < 3072) {
        transpose_tile(Wp, WpT, 3072, (blk % 96) * 32, (blk / 96) * 32, T);
    } else {
        const size_t i = (size_t)(blk - 3072) * 256 + threadIdx.x;
        const float4* p = (const float4*)x + i * 2;
        float4 a = p[0], b = p[1];
        uint4 o;
        o.x = pack2(a.x, a.y); o.y = pack2(a.z, a.w);
        o.z = pack2(b.x, b.y); o.w = pack2(b.z, b.w);
        ((uint4*)xbf)[i] = o;
    }
}

// ---- One-time W (K=1024 x N fp32) -> WT (N x 1024 bf16) transpose ----
__global__ __launch_bounds__(256) void transpose_w(
    const float* __restrict__ W, uint16_t* __restrict__ WT, int N)
{
    __shared__ float T[32][33];
    transpose_tile(W, WT, N, blockIdx.x * 32, blockIdx.y * 32, T);
}

// ---- Reg-staging macros (fp32-A fallback path; 512 threads, 8 elems/thread) ----
#define LOADK(K0, A_, B_)                                                                  \
    do {                                                                                   \
        if (ABF) {                                                                         \
            const uint16_t* ap_ = (const uint16_t*)Araw + (size_t)(m0 + sm) * 1024 + (K0) + skc; \
            A_ = *(const uint4*)ap_;                                                       \
        } else {                                                                           \
            const float* ap_ = (const float*)Araw + (size_t)(m0 + sm) * 1024 + (K0) + skc; \
            float4 f0_ = *(const float4*)(ap_ + 0),  f1_ = *(const float4*)(ap_ + 4);      \
            A_.x = pack2(f0_.x, f0_.y); A_.y = pack2(f0_.z, f0_.w);                        \
            A_.z = pack2(f1_.x, f1_.y); A_.w = pack2(f1_.z, f1_.w);                        \
        }                                                                                  \
        const uint16_t* bp_ = BT + (size_t)(n0 + sm) * 1024 + (K0) + skc;                  \
        B_ = *(const uint4*)bp_;                                                           \
    } while (0)

#define STOREK(BUF, A_, B_)                                                                \
    do {                                                                                   \
        *(uint4*)&As[BUF][sm][skc] = A_;                                                   \
        *(uint4*)&Bs[BUF][sm][skc] = B_;                                                   \
    } while (0)

// 8-wave compute: per-wave 32x64 output -> acc[2][4], 8 MFMA per k-step.
#define COMPUTEK(BUF)                                                                      \
    do {                                                                                   \
        bf16x8 af_[2], bf_[4];                                                             \
        _Pragma("unroll")                                                                  \
        for (int mi = 0; mi < 2; ++mi)                                                     \
            af_[mi] = *(const bf16x8*)&As[BUF][wm + mi * 16 + li][quad * 8];               \
        _Pragma("unroll")                                                                  \
        for (int ni = 0; ni < 4; ++ni)                                                     \
            bf_[ni] = *(const bf16x8*)&Bs[BUF][wn + ni * 16 + li][quad * 8];               \
        _Pragma("unroll")                                                                  \
        for (int mi = 0; mi < 2; ++mi)                                                     \
            _Pragma("unroll")                                                              \
            for (int ni = 0; ni < 4; ++ni)                                                 \
                acc[mi][ni] = mfma16(af_[mi], bf_[ni], acc[mi][ni]);                       \
    } while (0)

// Async global->LDS staging, 512 threads: ONE global_load_lds per operand covers
// the full 128x32 tile (512 lanes x 16B). Wave w's lanes fill rows [w*16,w*16+16).
#define STAGE_GLL(BUF, K0)                                                                 \
    do {                                                                                   \
        const uint16_t* ga_ = (const uint16_t*)Araw +                                      \
            (size_t)(m0 + wave * 16 + (lane >> 2)) * 1024 + (K0) + (lane & 3) * 8;         \
        __builtin_amdgcn_global_load_lds(                                                  \
            (const __attribute__((address_space(1))) void*)ga_,                            \
            (__attribute__((address_space(3))) void*)&As[BUF][wave * 16][0], 16, 0, 0);    \
        const uint16_t* gb_ = BT +                                                         \
            (size_t)(n0 + wave * 16 + (lane >> 2)) * 1024 + (K0) + (lane & 3) * 8;         \
        __builtin_amdgcn_global_load_lds(                                                  \
            (const __attribute__((address_space(1))) void*)gb_,                            \
            (__attribute__((address_space(3))) void*)&Bs[BUF][wave * 16][0], 16, 0, 0);    \
    } while (0)

// ---- MFMA GEMM: C(M x N) = A(M x 1024) @ BT^T + bias ----
// 512 threads / 8 waves (4m x 2n), 128x128 tile, double-buffered GLL staging.
// MODE 0: N=3072 fused RoPE/split epilogue (WV: also emit V as bf16 [bh][hd][s]);
//         q pre-scaled by 0.125*log2(e) so attn uses native exp2. MODE 1: fp32 out.
template<int MODE, bool ABF, bool WV>
__global__ __launch_bounds__(512) void gemm_mfma(
    const void* __restrict__ Araw,
    const uint16_t* __restrict__ BT,
    const float* __restrict__ bias,
    int N,
    const float* __restrict__ cq, const float* __restrict__ sq,
    const float* __restrict__ ck, const float* __restrict__ sk,
    uint16_t* __restrict__ qbuf, uint16_t* __restrict__ kbuf,
    float* __restrict__ kout, float* __restrict__ vout,
    uint16_t* __restrict__ vtb,
    float* __restrict__ Cout)
{
    __shared__ uint16_t As[2][128][32];   // linear (GLL requires contiguous dest)
    __shared__ uint16_t Bs[2][128][32];

    const int tid  = threadIdx.x;
    const int wave = tid >> 6, lane = tid & 63;
    const int quad = lane >> 4, li = lane & 15;
    const int wm = (wave >> 1) * 32, wn = (wave & 1) * 64;
    const int m0 = blockIdx.y * 128, n0 = blockIdx.x * 128;

    f32x4 acc[2][4];
    #pragma unroll
    for (int a = 0; a < 2; ++a)
        #pragma unroll
        for (int c = 0; c < 4; ++c)
            acc[a][c] = (f32x4){0.f, 0.f, 0.f, 0.f};

    const int sm = tid >> 2, skc = (tid & 3) * 8;

    if constexpr (ABF) {
        STAGE_GLL(0, 0);
        __syncthreads();                        // vmcnt drained -> buf0 ready
        for (int t = 0; t < 32; t += 2) {
            if (t + 1 < 32) STAGE_GLL(1, (t + 1) * 32);   // async under compute
            COMPUTEK(0);
            __syncthreads();                    // buf1 ready; all done reading buf0
            if (t + 2 < 32) STAGE_GLL(0, (t + 2) * 32);
            COMPUTEK(1);
            __syncthreads();
        }
    } else {
        uint4 Aa, Ba, Ab, Bb;
        LOADK(0, Aa, Ba);
        STOREK(0, Aa, Ba);
        LOADK(32, Ab, Bb);
        __syncthreads();
        for (int t = 0; t < 16; ++t) {
            const int kb = t * 64;
            if (t < 15) LOADK(kb + 64, Aa, Ba);
            COMPUTEK(0);
            STOREK(1, Ab, Bb);
            __syncthreads();
            if (t < 15) LOADK(kb + 96, Ab, Bb);
            COMPUTEK(1);
            if (t < 15) {
                STOREK(0, Aa, Ba);
                __syncthreads();
            }
        }
    }

    if (MODE == 1) {
        #pragma unroll
        for (int ni = 0; ni < 4; ++ni) {
            const int n = n0 + wn + ni * 16 + li;
            const float bb = bias[n];
            #pragma unroll
            for (int mi = 0; mi < 2; ++mi)
                #pragma unroll
                for (int r = 0; r < 4; ++r) {
                    const int m = m0 + wm + mi * 16 + quad * 4 + r;
                    Cout[(size_t)m * N + n] = acc[mi][ni][r] + bb;
                }
        }
    } else {
        #pragma unroll
        for (int ni = 0; ni < 4; ++ni) {
            const int n   = n0 + wn + ni * 16 + li;
            const int sel = n >> 10;        // 0=q 1=k 2=v (wave-uniform per ni)
            const int d   = n & 1023;
            const int h   = d >> 6;
            const int hd  = d & 63;
            const int i0  = hd >> 1;
            const float bb = bias[n];
            #pragma unroll
            for (int mi = 0; mi < 2; ++mi) {
                const int mb = m0 + wm + mi * 16 + quad * 4;
                const int b  = mb >> 11;
                const int s0 = mb & 2047;
                float vv[4];
                #pragma unroll
                for (int r = 0; r < 4; ++r) {
                    const int s = s0 + r;
                    const float val  = acc[mi][ni][r] + bb;
                    const float part = __shfl_xor(val, 1);   // RoPE partner (n^1)
                    const size_t idx = ((size_t)(b * NH + h) * S_LEN + s) * HS + hd;
                    if (sel == 0) {
                        float c = cq[s * 32 + i0], sn = sq[s * 32 + i0];
                        float o = (hd & 1) ? (part * sn + val * c) : (val * c - part * sn);
                        qbuf[idx] = f2b(o * 0.18033688f);    // 1/sqrt(HS) * log2(e)
                    } else if (sel == 1) {
                        kout[idx] = val;                     // kv[0] = pre-rotary k
                        float c = ck[s * 32 + i0], sn = sk[s * 32 + i0];
                        float o = (hd & 1) ? (part * sn + val * c) : (val * c - part * sn);
                        kbuf[idx] = f2b(o);
                    } else {
                        vout[idx] = val;                     // kv[1] = v
                        vv[r] = val;
                    }
                }
                if (WV && sel == 2) {
                    u16x4 u;
                    u[0] = f2b(vv[0]); u[1] = f2b(vv[1]);
                    u[2] = f2b(vv[2]); u[3] = f2b(vv[3]);
                    *(u16x4*)&vtb[((size_t)(b * NH + h) * HS + hd) * S_LEN + s0] = u;
                }
            }
        }
    }
}

// ---- MFMA flash attention ----
// Block = (b,h) x PAIR of 64-query tiles {pr, 31-pr} processed sequentially:
// every block does exactly 33 kv-iterations -> uniform makespan, no drain tail
// (R9 diagnosis: occupancy 18.8% was the variable-qt tail). Grid 512, 4 waves.
// V pre-transposed bf16 [bh][hd][s]. Q frags direct from global. Softmax in log2
// domain; row-max via DPP; row-sum via MFMA ones-B.
__global__ __launch_bounds__(256) void attn_mfma(
    const uint16_t* __restrict__ qbuf,
    const uint16_t* __restrict__ kbuf,
    const uint16_t* __restrict__ vtb,
    uint16_t* __restrict__ obuf)
{
    __shared__ uint16_t Ks[64][72];
    __shared__ uint16_t Vt[64][72];   // [hs][key]
    __shared__ uint16_t Ps[64][68];   // stride 68 (34 dw): conflict-free writes+reads

    const int i  = blockIdx.x;
    const int bh = i >> 4;
    const int pr = i & 15;
    const int h = bh & 15, b = bh >> 4;
    const int tid = threadIdx.x;
    const int wave = tid >> 6, lane = tid & 63;
    const int quad = lane >> 4, li = lane & 15;
    const int wrow0 = wave * 16;

    const short onebf = (short)0x3F80;   // bf16 1.0
    const bf16x8 kOnes = {onebf, onebf, onebf, onebf, onebf, onebf, onebf, onebf};

    const int row = tid >> 2, c = (tid & 3) * 16;         // shared staging coords
    uint4 kr0, kr1, vr0, vr1;

    auto load_kv = [&](int kt) {
        const uint16_t* kp = kbuf + ((size_t)bh * S_LEN + kt * 64 + row) * HS + c;
        kr0 = *(const uint4*)kp;
        kr1 = *(const uint4*)(kp + 8);
        const uint16_t* vp = vtb + ((size_t)bh * HS + row) * S_LEN + kt * 64 + c;
        vr0 = *(const uint4*)vp;
        vr1 = *(const uint4*)(vp + 8);
    };
    load_kv(0);

    for (int tt = 0; tt < 2; ++tt) {
        const int qt = tt ? (31 - pr) : pr;

        // Q fragments direct from global: rows wrow0+li, cols quad*8(+32)
        const uint16_t* qp = qbuf + ((size_t)bh * S_LEN + qt * 64 + wrow0 + li) * HS + quad * 8;
        const bf16x8 aq0 = *(const bf16x8*)qp;
        const bf16x8 aq1 = *(const bf16x8*)(qp + 32);

        f32x4 oacc[4];
        float m_i[4], l_i[4];
        #pragma unroll
        for (int r = 0; r < 4; ++r) {
            m_i[r] = -1e30f; l_i[r] = 0.f;
            oacc[r] = (f32x4){0.f, 0.f, 0.f, 0.f};
        }

        for (int kt = 0; kt <= qt; ++kt) {
            __syncthreads();   // previous iteration's LDS consumers done
            *(uint4*)&Ks[row][c]     = kr0;
            *(uint4*)&Ks[row][c + 8] = kr1;
            *(uint4*)&Vt[row][c]     = vr0;
            *(uint4*)&Vt[row][c + 8] = vr1;
            __syncthreads();
            if (kt < qt)       load_kv(kt + 1);   // prefetch next tile
            else if (tt == 0)  load_kv(0);        // prefetch tile B's first kv

            // S' = Q' K^T in log2 domain (q pre-scaled by 0.125*log2e)
            f32x4 sacc[4];
            __builtin_amdgcn_s_setprio(1);
            #pragma unroll
            for (int ni = 0; ni < 4; ++ni) {
                bf16x8 b0 = *(const bf16x8*)&Ks[ni * 16 + li][quad * 8];
                bf16x8 b1 = *(const bf16x8*)&Ks[ni * 16 + li][32 + quad * 8];
                f32x4 z = (f32x4){0.f, 0.f, 0.f, 0.f};
                z = mfma16(aq0, b0, z);
                sacc[ni] = mfma16(aq1, b1, z);
            }
            __builtin_amdgcn_s_setprio(0);

            // online softmax (C-layout: row = quad*4+r, col = ni*16+li)
            const bool diag = (kt == qt);
            float p[4][4];
            #pragma unroll
            for (int ni = 0; ni < 4; ++ni)
                #pragma unroll
                for (int r = 0; r < 4; ++r) {
                    float v = sacc[ni][r];
                    if (diag && (ni * 16 + li > wrow0 + quad * 4 + r)) v = -65504.f;
                    p[ni][r] = v;
                }
            float alp[4];
            #pragma unroll
            for (int r = 0; r < 4; ++r) {
                float mx = fmaxf(fmaxf(p[0][r], p[1][r]), fmaxf(p[2][r], p[3][r]));
                mx = dpp_max<0xB1>(mx);    // quad_perm [1,0,3,2]  (xor 1)
                mx = dpp_max<0x4E>(mx);    // quad_perm [2,3,0,1]  (xor 2)
                mx = dpp_max<0x124>(mx);   // row_ror:4
                mx = dpp_max<0x128>(mx);   // row_ror:8  -> all-16-lane max
                float mnew  = fmaxf(m_i[r], mx);
                alp[r] = fast_exp2(m_i[r] - mnew);
                m_i[r] = mnew;
                #pragma unroll
                for (int ni = 0; ni < 4; ++ni)
                    p[ni][r] = fast_exp2(p[ni][r] - mnew);
                #pragma unroll
                for (int ni = 0; ni < 4; ++ni) oacc[ni][r] *= alp[r];
            }

            // P: C-layout -> A-layout via wave-private LDS slab
            #pragma unroll
            for (int ni = 0; ni < 4; ++ni)
                #pragma unroll
                for (int r = 0; r < 4; ++r)
                    Ps[wrow0 + quad * 4 + r][ni * 16 + li] = f2b(p[ni][r]);

            bf16x8 pa0 = *(const bf16x8*)&Ps[wrow0 + li][quad * 8];
            bf16x8 pa1 = *(const bf16x8*)&Ps[wrow0 + li][32 + quad * 8];

            // row-sum via MFMA with B=ones: ls[r] matches sacc's per-lane slot
            __builtin_amdgcn_s_setprio(1);
            f32x4 ls = (f32x4){0.f, 0.f, 0.f, 0.f};
            ls = mfma16(pa0, kOnes, ls);
            ls = mfma16(pa1, kOnes, ls);

            // O += P @ V
            #pragma unroll
            for (int ni = 0; ni < 4; ++ni) {
                bf16x8 v0 = *(const bf16x8*)&Vt[ni * 16 + li][quad * 8];
                bf16x8 v1 = *(const bf16x8*)&Vt[ni * 16 + li][32 + quad * 8];
                oacc[ni] = mfma16(pa0, v0, oacc[ni]);
                oacc[ni] = mfma16(pa1, v1, oacc[ni]);
            }
            __builtin_amdgcn_s_setprio(0);

            #pragma unroll
            for (int r = 0; r < 4; ++r)
                l_i[r] = l_i[r] * alp[r] + ls[r];
        }

        #pragma unroll
        for (int ni = 0; ni < 4; ++ni)
            #pragma unroll
            for (int r = 0; r < 4; ++r) {
                const int qg = qt * 64 + wrow0 + quad * 4 + r;
                obuf[((size_t)b * S_LEN + qg) * DM + h * HS + ni * 16 + li] =
                    f2b(oacc[ni][r] / l_i[r]);
            }
    }
}

extern "C" void kernel_launch(void* const* d_in, const int* in_sizes, int n_in,
                              void* d_out, int out_size, void* d_ws, size_t ws_size,
                              hipStream_t stream) {
    const float* x  = (const float*)d_in[0];
    const float* cq = (const float*)d_in[1];
    const float* sq = (const float*)d_in[2];
    const float* ck = (const float*)d_in[3];
    const float* sk = (const float*)d_in[4];
    // d_in[5]: causal tril mask (int32) — structure known, not re-read
    const float* Wp = (const float*)d_in[6];
    const float* bp = (const float*)d_in[7];
    const float* Wf = (const float*)d_in[8];
    const float* bf = (const float*)d_in[9];

    float* out  = (float*)d_out;
    float* ffo  = out;                 // (B,S,DM) fp32
    float* kout = out + 4194304;       // kv[0] = pre-rotary k (B,NH,S,HS) fp32
    float* vout = out + 8388608;       // kv[1] = v fp32

    uint16_t* qbuf = (uint16_t*)d_ws;  // RoPE'd q bf16 (pre-scaled)    [0,8M)
    uint16_t* kbuf = qbuf + 4194304;   // RoPE'd k bf16                 [8M,16M)
    uint16_t* abuf = kbuf + 4194304;   // attn_o bf16                   [16M,24M)
    uint16_t* vtb  = abuf + 4194304;   // V bf16 [bh][hd][s]            [24M,32M)
    uint16_t* xbf  = vtb  + 4194304;   // x bf16                        [32M,40M)
    uint16_t* WpT  = abuf;             // alias: dead before attn writes abuf
    uint16_t* WfT  = qbuf;             // alias: qbuf dead after attn

    const bool has_xbf = ws_size >= (size_t)40 * 1024 * 1024;

    dim3 blk(256), blkg(512);
    if (has_xbf) {
        prep<<<dim3(5120), blk, 0, stream>>>(x, xbf, Wp, WpT);
        gemm_mfma<0, true, true><<<dim3(24, 32), blkg, 0, stream>>>(
            xbf, WpT, bp, 3072, cq, sq, ck, sk,
            qbuf, kbuf, kout, vout, vtb, nullptr);
    } else {
        transpose_w<<<dim3(96, 32), blk, 0, stream>>>(Wp, WpT, 3072);
        gemm_mfma<0, false, true><<<dim3(24, 32), blkg, 0, stream>>>(
            x, WpT, bp, 3072, cq, sq, ck, sk,
            qbuf, kbuf, kout, vout, vtb, nullptr);
    }
    attn_mfma<<<dim3(512), blk, 0, stream>>>(qbuf, kbuf, vtb, abuf);
    transpose_w<<<dim3(32, 32), blk, 0, stream>>>(Wf, WfT, 1024);
    gemm_mfma<1, true, false><<<dim3(8, 32), blkg, 0, stream>>>(
        abuf, WfT, bf, 1024, nullptr, nullptr, nullptr, nullptr,
        nullptr, nullptr, nullptr, nullptr, nullptr, ffo);
}

// Round 11
// 244.462 us; speedup vs baseline: 1.2037x; 1.0273x over previous
//
#include <hip/hip_runtime.h>
#include <stdint.h>

#define DM    1024
#define NH    16
#define HS    64
#define S_LEN 2048

typedef short bf16x8 __attribute__((ext_vector_type(8)));
typedef float f32x4  __attribute__((ext_vector_type(4)));
typedef unsigned short u16x4 __attribute__((ext_vector_type(4)));

__device__ __forceinline__ uint16_t f2b(float f) {
    union { float f; uint32_t i; } x; x.f = f;
    uint32_t r = x.i + 0x7fffu + ((x.i >> 16) & 1u);
    return (uint16_t)(r >> 16);
}
__device__ __forceinline__ uint32_t pack2(float a, float b) {
    return (uint32_t)f2b(a) | ((uint32_t)f2b(b) << 16);
}
__device__ __forceinline__ f32x4 mfma16(bf16x8 a, bf16x8 b, f32x4 c) {
    return __builtin_amdgcn_mfma_f32_16x16x32_bf16(a, b, c, 0, 0, 0);
}
// native 2^x (one v_exp_f32). NOTE: __exp2f does not exist in this toolchain.
__device__ __forceinline__ float fast_exp2(float x) {
    return __builtin_amdgcn_exp2f(x);
}
// 16-lane-row max reduce step via DPP (VALU pipe, no LDS). CTRL must be an ICE.
template<int CTRL>
__device__ __forceinline__ float dpp_max(float x) {
    union { float f; int i; } u; u.f = x;
    int y = __builtin_amdgcn_update_dpp(u.i, u.i, CTRL, 0xF, 0xF, true);
    union { int i; float f; } v; v.i = y;
    return fmaxf(x, v.f);
}

// ---- 32x32 fp32 -> bf16 transposed tile (shared by prep / transpose_w) ----
__device__ __forceinline__ void transpose_tile(
    const float* __restrict__ W, uint16_t* __restrict__ WT, int N,
    int n0, int k0, float (*T)[33])
{
    const int tx = threadIdx.x & 31, ty = threadIdx.x >> 5;
    #pragma unroll
    for (int i = 0; i < 4; ++i)
        T[ty + i * 8][tx] = W[(size_t)(k0 + ty + i * 8) * N + n0 + tx];
    __syncthreads();
    #pragma unroll
    for (int i = 0; i < 4; ++i)
        WT[(size_t)(n0 + ty + i * 8) * 1024 + k0 + tx] = f2b(T[tx][ty + i * 8]);
}

// ---- Fused prep: blocks [0,3072) transpose Wp; [3072,5120) convert x -> bf16 ----
__global__ __launch_bounds__(256) void prep(
    const float* __restrict__ x, uint16_t* __restrict__ xbf,
    const float* __restrict__ Wp, uint16_t* __restrict__ WpT)
{
    __shared__ float T[32][33];
    const int blk = blockIdx.x;
    if (blk < 3072) {
        transpose_tile(Wp, WpT, 3072, (blk % 96) * 32, (blk / 96) * 32, T);
    } else {
        const size_t i = (size_t)(blk - 3072) * 256 + threadIdx.x;
        const float4* p = (const float4*)x + i * 2;
        float4 a = p[0], b = p[1];
        uint4 o;
        o.x = pack2(a.x, a.y); o.y = pack2(a.z, a.w);
        o.z = pack2(b.x, b.y); o.w = pack2(b.z, b.w);
        ((uint4*)xbf)[i] = o;
    }
}

// ---- One-time W (K=1024 x N fp32) -> WT (N x 1024 bf16) transpose ----
__global__ __launch_bounds__(256) void transpose_w(
    const float* __restrict__ W, uint16_t* __restrict__ WT, int N)
{
    __shared__ float T[32][33];
    transpose_tile(W, WT, N, blockIdx.x * 32, blockIdx.y * 32, T);
}

#define GLL16(SRC, DST)                                                                    \
    __builtin_amdgcn_global_load_lds(                                                      \
        (const __attribute__((address_space(1))) void*)(SRC),                              \
        (__attribute__((address_space(3))) void*)(DST), 16, 0, 0)

// Async global->LDS staging, 256 threads / 4 waves, BK=64 (128B rows):
// 1 GLL chunk = 64 lanes x 16B = 8 rows. A tile 128x64: 4 chunks/wave.
// B tile 64x64: 2 chunks/wave. Dest base wave-uniform (HW rule).
#define STAGE_GLL(BUF, K0)                                                                 \
    do {                                                                                   \
        const uint16_t* ga_ = (const uint16_t*)Araw +                                      \
            (size_t)(m0 + wave * 32 + (lane >> 3)) * 1024 + (K0) + (lane & 7) * 8;         \
        GLL16(ga_,             &As[BUF][wave * 32 +  0][0]);                               \
        GLL16(ga_ +  8 * 1024, &As[BUF][wave * 32 +  8][0]);                               \
        GLL16(ga_ + 16 * 1024, &As[BUF][wave * 32 + 16][0]);                               \
        GLL16(ga_ + 24 * 1024, &As[BUF][wave * 32 + 24][0]);                               \
        const uint16_t* gb_ = BT +                                                         \
            (size_t)(n0 + wave * 16 + (lane >> 3)) * 1024 + (K0) + (lane & 7) * 8;         \
        GLL16(gb_,             &Bs[BUF][wave * 16 + 0][0]);                                 \
        GLL16(gb_ +  8 * 1024, &Bs[BUF][wave * 16 + 8][0]);                                 \
    } while (0)

// 4-wave compute, BK=64: per-wave 32x64 output, acc[2][4], 16 MFMA per k-step.
#define COMPUTEK(BUF)                                                                      \
    do {                                                                                   \
        bf16x8 a0_[2], a1_[2], b0_[4], b1_[4];                                             \
        _Pragma("unroll")                                                                  \
        for (int mi = 0; mi < 2; ++mi) {                                                   \
            a0_[mi] = *(const bf16x8*)&As[BUF][wm + mi * 16 + li][quad * 8];               \
            a1_[mi] = *(const bf16x8*)&As[BUF][wm + mi * 16 + li][32 + quad * 8];          \
        }                                                                                  \
        _Pragma("unroll")                                                                  \
        for (int ni = 0; ni < 4; ++ni) {                                                   \
            b0_[ni] = *(const bf16x8*)&Bs[BUF][ni * 16 + li][quad * 8];                    \
            b1_[ni] = *(const bf16x8*)&Bs[BUF][ni * 16 + li][32 + quad * 8];               \
        }                                                                                  \
        _Pragma("unroll")                                                                  \
        for (int mi = 0; mi < 2; ++mi)                                                     \
            _Pragma("unroll")                                                              \
            for (int ni = 0; ni < 4; ++ni)                                                 \
                acc[mi][ni] = mfma16(a0_[mi], b0_[ni], acc[mi][ni]);                       \
        _Pragma("unroll")                                                                  \
        for (int mi = 0; mi < 2; ++mi)                                                     \
            _Pragma("unroll")                                                              \
            for (int ni = 0; ni < 4; ++ni)                                                 \
                acc[mi][ni] = mfma16(a1_[mi], b1_[ni], acc[mi][ni]);                       \
    } while (0)

// ---- MFMA GEMM: C(M x N) = A(M x 1024) @ BT^T + bias ----
// Tile 128(M) x 64(N), BK=64, 256 threads / 4 waves: 16 k-steps (half the barrier
// drains of BK=32), grid 2x larger (gemm0 6 blocks/CU), LDS 48KB -> 3 blocks/CU.
// MODE 0: N=3072 fused RoPE/split epilogue (WV: also emit V as bf16 [bh][hd][s]);
//         q pre-scaled by 0.125*log2(e) so attn uses native exp2. MODE 1: fp32 out.
template<int MODE, bool ABF, bool WV>
__global__ __launch_bounds__(256) void gemm_mfma(
    const void* __restrict__ Araw,
    const uint16_t* __restrict__ BT,
    const float* __restrict__ bias,
    int N,
    const float* __restrict__ cq, const float* __restrict__ sq,
    const float* __restrict__ ck, const float* __restrict__ sk,
    uint16_t* __restrict__ qbuf, uint16_t* __restrict__ kbuf,
    float* __restrict__ kout, float* __restrict__ vout,
    uint16_t* __restrict__ vtb,
    float* __restrict__ Cout)
{
    __shared__ uint16_t As[2][128][64];   // linear (GLL requires contiguous dest)
    __shared__ uint16_t Bs[2][64][64];

    const int tid  = threadIdx.x;
    const int wave = tid >> 6, lane = tid & 63;
    const int quad = lane >> 4, li = lane & 15;
    const int wm = wave * 32;
    const int m0 = blockIdx.y * 128, n0 = blockIdx.x * 64;

    f32x4 acc[2][4];
    #pragma unroll
    for (int a = 0; a < 2; ++a)
        #pragma unroll
        for (int c = 0; c < 4; ++c)
            acc[a][c] = (f32x4){0.f, 0.f, 0.f, 0.f};

    if constexpr (ABF) {
        STAGE_GLL(0, 0);
        __syncthreads();                        // vmcnt drained -> buf0 ready
        for (int t = 0; t < 16; t += 2) {
            if (t + 1 < 16) STAGE_GLL(1, (t + 1) * 64);   // async under compute
            COMPUTEK(0);
            __syncthreads();                    // buf1 ready; all done reading buf0
            if (t + 2 < 16) STAGE_GLL(0, (t + 2) * 64);
            COMPUTEK(1);
            __syncthreads();
        }
    } else {
        // fp32-A fallback: single-buffer, reg-staged pack (rarely used)
        const int ar_ = tid >> 1, ac_ = (tid & 1) * 32;
        const int br_ = tid >> 2, bc_ = (tid & 3) * 16;
        for (int t = 0; t < 16; ++t) {
            const int K0 = t * 64;
            const float* ap_ = (const float*)Araw + (size_t)(m0 + ar_) * 1024 + K0 + ac_;
            uint4 aw0, aw1, aw2, aw3;
            {
                float4 f0 = *(const float4*)(ap_ + 0),  f1 = *(const float4*)(ap_ + 4);
                float4 f2 = *(const float4*)(ap_ + 8),  f3 = *(const float4*)(ap_ + 12);
                float4 f4 = *(const float4*)(ap_ + 16), f5 = *(const float4*)(ap_ + 20);
                float4 f6 = *(const float4*)(ap_ + 24), f7 = *(const float4*)(ap_ + 28);
                aw0.x = pack2(f0.x, f0.y); aw0.y = pack2(f0.z, f0.w);
                aw0.z = pack2(f1.x, f1.y); aw0.w = pack2(f1.z, f1.w);
                aw1.x = pack2(f2.x, f2.y); aw1.y = pack2(f2.z, f2.w);
                aw1.z = pack2(f3.x, f3.y); aw1.w = pack2(f3.z, f3.w);
                aw2.x = pack2(f4.x, f4.y); aw2.y = pack2(f4.z, f4.w);
                aw2.z = pack2(f5.x, f5.y); aw2.w = pack2(f5.z, f5.w);
                aw3.x = pack2(f6.x, f6.y); aw3.y = pack2(f6.z, f6.w);
                aw3.z = pack2(f7.x, f7.y); aw3.w = pack2(f7.z, f7.w);
            }
            const uint16_t* bp_ = BT + (size_t)(n0 + br_) * 1024 + K0 + bc_;
            uint4 bw0 = *(const uint4*)bp_;
            uint4 bw1 = *(const uint4*)(bp_ + 8);
            __syncthreads();
            *(uint4*)&As[0][ar_][ac_]      = aw0;
            *(uint4*)&As[0][ar_][ac_ + 8]  = aw1;
            *(uint4*)&As[0][ar_][ac_ + 16] = aw2;
            *(uint4*)&As[0][ar_][ac_ + 24] = aw3;
            *(uint4*)&Bs[0][br_][bc_]      = bw0;
            *(uint4*)&Bs[0][br_][bc_ + 8]  = bw1;
            __syncthreads();
            COMPUTEK(0);
        }
    }

    if (MODE == 1) {
        #pragma unroll
        for (int ni = 0; ni < 4; ++ni) {
            const int n = n0 + ni * 16 + li;
            const float bb = bias[n];
            #pragma unroll
            for (int mi = 0; mi < 2; ++mi)
                #pragma unroll
                for (int r = 0; r < 4; ++r) {
                    const int m = m0 + wm + mi * 16 + quad * 4 + r;
                    Cout[(size_t)m * N + n] = acc[mi][ni][r] + bb;
                }
        }
    } else {
        #pragma unroll
        for (int ni = 0; ni < 4; ++ni) {
            const int n   = n0 + ni * 16 + li;
            const int sel = n >> 10;        // 0=q 1=k 2=v (uniform per block)
            const int d   = n & 1023;
            const int h   = d >> 6;
            const int hd  = d & 63;
            const int i0  = hd >> 1;
            const float bb = bias[n];
            #pragma unroll
            for (int mi = 0; mi < 2; ++mi) {
                const int mb = m0 + wm + mi * 16 + quad * 4;
                const int b  = mb >> 11;
                const int s0 = mb & 2047;
                float vv[4];
                #pragma unroll
                for (int r = 0; r < 4; ++r) {
                    const int s = s0 + r;
                    const float val  = acc[mi][ni][r] + bb;
                    const float part = __shfl_xor(val, 1);   // RoPE partner (n^1)
                    const size_t idx = ((size_t)(b * NH + h) * S_LEN + s) * HS + hd;
                    if (sel == 0) {
                        float c = cq[s * 32 + i0], sn = sq[s * 32 + i0];
                        float o = (hd & 1) ? (part * sn + val * c) : (val * c - part * sn);
                        qbuf[idx] = f2b(o * 0.18033688f);    // 1/sqrt(HS) * log2(e)
                    } else if (sel == 1) {
                        kout[idx] = val;                     // kv[0] = pre-rotary k
                        float c = ck[s * 32 + i0], sn = sk[s * 32 + i0];
                        float o = (hd & 1) ? (part * sn + val * c) : (val * c - part * sn);
                        kbuf[idx] = f2b(o);
                    } else {
                        vout[idx] = val;                     // kv[1] = v
                        vv[r] = val;
                    }
                }
                if (WV && sel == 2) {
                    u16x4 u;
                    u[0] = f2b(vv[0]); u[1] = f2b(vv[1]);
                    u[2] = f2b(vv[2]); u[3] = f2b(vv[3]);
                    *(u16x4*)&vtb[((size_t)(b * NH + h) * HS + hd) * S_LEN + s0] = u;
                }
            }
        }
    }
}

// ---- MFMA flash attention ----
// Block = (b,h) x pair {pr, 31-pr} sequential; KVBLK=128 (2 kv-64-tiles per
// staging/barrier pair): ceil((pr+1)/2) + ceil((32-pr)/2) = 17 steps for EVERY
// block -> uniform makespan with HALF the barrier drains of KVBLK=64.
// V pre-transposed bf16 [bh][hd][s]. Q frags direct from global. Softmax in log2
// domain; row-max via DPP; row-sum via MFMA ones-B.
__global__ __launch_bounds__(256) void attn_mfma(
    const uint16_t* __restrict__ qbuf,
    const uint16_t* __restrict__ kbuf,
    const uint16_t* __restrict__ vtb,
    uint16_t* __restrict__ obuf)
{
    __shared__ uint16_t Ks[128][72];   // [key][hs]
    __shared__ uint16_t Vt[64][136];   // [hs][key]
    __shared__ uint16_t Ps[64][136];   // wave-private 16-row slabs, 128 cols

    const int i  = blockIdx.x;
    const int bh = i >> 4;
    const int pr = i & 15;
    const int h = bh & 15, b = bh >> 4;
    const int tid = threadIdx.x;
    const int wave = tid >> 6, lane = tid & 63;
    const int quad = lane >> 4, li = lane & 15;
    const int wrow0 = wave * 16;

    const short onebf = (short)0x3F80;   // bf16 1.0
    const bf16x8 kOnes = {onebf, onebf, onebf, onebf, onebf, onebf, onebf, onebf};

    const int krow = tid >> 1, kc = (tid & 1) * 32;   // K staging: 128 x 64
    const int vrow = tid >> 2, vc = (tid & 3) * 32;   // Vt staging: 64 x 128
    uint4 kr0, kr1, kr2, kr3, vr0, vr1, vr2, vr3;

    auto load_kv = [&](int s2) {   // keys [s2*128, s2*128+128)
        const uint16_t* kp = kbuf + ((size_t)bh * S_LEN + s2 * 128 + krow) * HS + kc;
        kr0 = *(const uint4*)kp;         kr1 = *(const uint4*)(kp + 8);
        kr2 = *(const uint4*)(kp + 16);  kr3 = *(const uint4*)(kp + 24);
        const uint16_t* vp = vtb + ((size_t)bh * HS + vrow) * S_LEN + s2 * 128 + vc;
        vr0 = *(const uint4*)vp;         vr1 = *(const uint4*)(vp + 8);
        vr2 = *(const uint4*)(vp + 16);  vr3 = *(const uint4*)(vp + 24);
    };
    load_kv(0);

    for (int tt = 0; tt < 2; ++tt) {
        const int qt  = tt ? (31 - pr) : pr;
        const int nst = (qt + 2) >> 1;           // ceil((qt+1)/2) 128-wide steps

        // Q fragments direct from global: rows wrow0+li, cols quad*8(+32)
        const uint16_t* qp = qbuf + ((size_t)bh * S_LEN + qt * 64 + wrow0 + li) * HS + quad * 8;
        const bf16x8 aq0 = *(const bf16x8*)qp;
        const bf16x8 aq1 = *(const bf16x8*)(qp + 32);

        f32x4 oacc[4];
        float m_i[4], l_i[4];
        #pragma unroll
        for (int r = 0; r < 4; ++r) {
            m_i[r] = -1e30f; l_i[r] = 0.f;
            oacc[r] = (f32x4){0.f, 0.f, 0.f, 0.f};
        }

        for (int s = 0; s < nst; ++s) {
            __syncthreads();   // previous step's LDS consumers done
            *(uint4*)&Ks[krow][kc]      = kr0;
            *(uint4*)&Ks[krow][kc + 8]  = kr1;
            *(uint4*)&Ks[krow][kc + 16] = kr2;
            *(uint4*)&Ks[krow][kc + 24] = kr3;
            *(uint4*)&Vt[vrow][vc]      = vr0;
            *(uint4*)&Vt[vrow][vc + 8]  = vr1;
            *(uint4*)&Vt[vrow][vc + 16] = vr2;
            *(uint4*)&Vt[vrow][vc + 24] = vr3;
            __syncthreads();
            if (s + 1 < nst)   load_kv(s + 1);   // prefetch under compute
            else if (tt == 0)  load_kv(0);       // prefetch tile B's first step

            // S' = Q' K^T over 128 keys (log2 domain, q pre-scaled)
            float p[8][4];
            __builtin_amdgcn_s_setprio(1);
            #pragma unroll
            for (int hf = 0; hf < 2; ++hf)
                #pragma unroll
                for (int ni = 0; ni < 4; ++ni) {
                    bf16x8 b0 = *(const bf16x8*)&Ks[hf * 64 + ni * 16 + li][quad * 8];
                    bf16x8 b1 = *(const bf16x8*)&Ks[hf * 64 + ni * 16 + li][32 + quad * 8];
                    f32x4 z = (f32x4){0.f, 0.f, 0.f, 0.f};
                    z = mfma16(aq0, b0, z);
                    z = mfma16(aq1, b1, z);
                    #pragma unroll
                    for (int r = 0; r < 4; ++r) p[hf * 4 + ni][r] = z[r];
                }
            __builtin_amdgcn_s_setprio(0);

            // causal mask: only the last step can cross the diagonal
            if (s == nst - 1) {
                #pragma unroll
                for (int g = 0; g < 8; ++g) {
                    const int col = s * 128 + g * 16 + li;
                    #pragma unroll
                    for (int r = 0; r < 4; ++r)
                        if (col > qt * 64 + wrow0 + quad * 4 + r) p[g][r] = -65504.f;
                }
            }

            float alp[4];
            #pragma unroll
            for (int r = 0; r < 4; ++r) {
                float mx = p[0][r];
                #pragma unroll
                for (int g = 1; g < 8; ++g) mx = fmaxf(mx, p[g][r]);
                mx = dpp_max<0xB1>(mx);    // quad_perm [1,0,3,2]
                mx = dpp_max<0x4E>(mx);    // quad_perm [2,3,0,1]
                mx = dpp_max<0x124>(mx);   // row_ror:4
                mx = dpp_max<0x128>(mx);   // row_ror:8 -> 16-lane max
                float mnew  = fmaxf(m_i[r], mx);
                alp[r] = fast_exp2(m_i[r] - mnew);
                m_i[r] = mnew;
                #pragma unroll
                for (int g = 0; g < 8; ++g)
                    p[g][r] = fast_exp2(p[g][r] - mnew);
                #pragma unroll
                for (int ni = 0; ni < 4; ++ni) oacc[ni][r] *= alp[r];
            }

            // P: C-layout -> A-layout via wave-private LDS slab (128 cols)
            #pragma unroll
            for (int g = 0; g < 8; ++g)
                #pragma unroll
                for (int r = 0; r < 4; ++r)
                    Ps[wrow0 + quad * 4 + r][g * 16 + li] = f2b(p[g][r]);

            bf16x8 pa0 = *(const bf16x8*)&Ps[wrow0 + li][quad * 8];
            bf16x8 pa1 = *(const bf16x8*)&Ps[wrow0 + li][32 + quad * 8];
            bf16x8 pa2 = *(const bf16x8*)&Ps[wrow0 + li][64 + quad * 8];
            bf16x8 pa3 = *(const bf16x8*)&Ps[wrow0 + li][96 + quad * 8];

            // row-sum via MFMA with B=ones (C-layout matches sacc)
            __builtin_amdgcn_s_setprio(1);
            f32x4 ls = (f32x4){0.f, 0.f, 0.f, 0.f};
            ls = mfma16(pa0, kOnes, ls);
            ls = mfma16(pa1, kOnes, ls);
            ls = mfma16(pa2, kOnes, ls);
            ls = mfma16(pa3, kOnes, ls);

            // O += P @ V  (K=128: 4 k-slices)
            #pragma unroll
            for (int ni = 0; ni < 4; ++ni) {
                bf16x8 v0 = *(const bf16x8*)&Vt[ni * 16 + li][quad * 8];
                bf16x8 v1 = *(const bf16x8*)&Vt[ni * 16 + li][32 + quad * 8];
                bf16x8 v2 = *(const bf16x8*)&Vt[ni * 16 + li][64 + quad * 8];
                bf16x8 v3 = *(const bf16x8*)&Vt[ni * 16 + li][96 + quad * 8];
                oacc[ni] = mfma16(pa0, v0, oacc[ni]);
                oacc[ni] = mfma16(pa1, v1, oacc[ni]);
                oacc[ni] = mfma16(pa2, v2, oacc[ni]);
                oacc[ni] = mfma16(pa3, v3, oacc[ni]);
            }
            __builtin_amdgcn_s_setprio(0);

            #pragma unroll
            for (int r = 0; r < 4; ++r)
                l_i[r] = l_i[r] * alp[r] + ls[r];
        }

        #pragma unroll
        for (int ni = 0; ni < 4; ++ni)
            #pragma unroll
            for (int r = 0; r < 4; ++r) {
                const int qg = qt * 64 + wrow0 + quad * 4 + r;
                obuf[((size_t)b * S_LEN + qg) * DM + h * HS + ni * 16 + li] =
                    f2b(oacc[ni][r] / l_i[r]);
            }
    }
}

extern "C" void kernel_launch(void* const* d_in, const int* in_sizes, int n_in,
                              void* d_out, int out_size, void* d_ws, size_t ws_size,
                              hipStream_t stream) {
    const float* x  = (const float*)d_in[0];
    const float* cq = (const float*)d_in[1];
    const float* sq = (const float*)d_in[2];
    const float* ck = (const float*)d_in[3];
    const float* sk = (const float*)d_in[4];
    // d_in[5]: causal tril mask (int32) — structure known, not re-read
    const float* Wp = (const float*)d_in[6];
    const float* bp = (const float*)d_in[7];
    const float* Wf = (const float*)d_in[8];
    const float* bf = (const float*)d_in[9];

    float* out  = (float*)d_out;
    float* ffo  = out;                 // (B,S,DM) fp32
    float* kout = out + 4194304;       // kv[0] = pre-rotary k (B,NH,S,HS) fp32
    float* vout = out + 8388608;       // kv[1] = v fp32

    uint16_t* qbuf = (uint16_t*)d_ws;  // RoPE'd q bf16 (pre-scaled)    [0,8M)
    uint16_t* kbuf = qbuf + 4194304;   // RoPE'd k bf16                 [8M,16M)
    uint16_t* abuf = kbuf + 4194304;   // attn_o bf16                   [16M,24M)
    uint16_t* vtb  = abuf + 4194304;   // V bf16 [bh][hd][s]            [24M,32M)
    uint16_t* xbf  = vtb  + 4194304;   // x bf16                        [32M,40M)
    uint16_t* WpT  = abuf;             // alias: dead before attn writes abuf
    uint16_t* WfT  = qbuf;             // alias: qbuf dead after attn

    const bool has_xbf = ws_size >= (size_t)40 * 1024 * 1024;

    dim3 blk(256);
    if (has_xbf) {
        prep<<<dim3(5120), blk, 0, stream>>>(x, xbf, Wp, WpT);
        gemm_mfma<0, true, true><<<dim3(48, 32), blk, 0, stream>>>(
            xbf, WpT, bp, 3072, cq, sq, ck, sk,
            qbuf, kbuf, kout, vout, vtb, nullptr);
    } else {
        transpose_w<<<dim3(96, 32), blk, 0, stream>>>(Wp, WpT, 3072);
        gemm_mfma<0, false, true><<<dim3(48, 32), blk, 0, stream>>>(
            x, WpT, bp, 3072, cq, sq, ck, sk,
            qbuf, kbuf, kout, vout, vtb, nullptr);
    }
    attn_mfma<<<dim3(512), blk, 0, stream>>>(qbuf, kbuf, vtb, abuf);
    transpose_w<<<dim3(32, 32), blk, 0, stream>>>(Wf, WfT, 1024);
    gemm_mfma<1, true, false><<<dim3(16, 32), blk, 0, stream>>>(
        abuf, WfT, bf, 1024, nullptr, nullptr, nullptr, nullptr,
        nullptr, nullptr, nullptr, nullptr, nullptr, ffo);
}